// Round 8
// baseline (138.288 us; speedup 1.0000x reference)
//
#include <hip/hip_runtime.h>
#include <stdint.h>

#define B_ROWS 4096
#define C_OUT  2048
#define C_IN   2048
#define EPS    1e-5f

typedef __attribute__((ext_vector_type(8))) short bf16x8;  // 8 bf16 = 4 VGPRs
typedef __attribute__((ext_vector_type(4))) float f32x4;

// RNE f32 -> bf16
__device__ __forceinline__ unsigned short f2bf(float f) {
    uint32_t u = __float_as_uint(f);
    uint32_t r = (u + 0x7fffu + ((u >> 16) & 1u)) >> 16;
    return (unsigned short)r;
}

// One launch converts both x and w (f32 -> bf16, float4-granular)
__global__ void cvt_f32_bf16_kernel(const float* __restrict__ x,
                                    const float* __restrict__ w,
                                    unsigned short* __restrict__ xb,
                                    unsigned short* __restrict__ wb,
                                    int nx4, int nw4) {
    int i = blockIdx.x * blockDim.x + threadIdx.x;
    const float* src;
    unsigned short* dst;
    if (i < nx4) {
        src = x; dst = xb;
    } else {
        i -= nx4;
        if (i >= nw4) return;
        src = w; dst = wb;
    }
    float4 v = ((const float4*)src)[i];
    ushort4 o;
    o.x = f2bf(v.x); o.y = f2bf(v.y); o.z = f2bf(v.z); o.w = f2bf(v.w);
    ((ushort4*)dst)[i] = o;
}

// Fused bf16 GEMM (C = A @ W^T + bias) + GroupNorm(32 groups of 64) + hardtanh.
// Tile 256x128 (staged L2 traffic 402 MB vs 537 at 128x128: A re-read 16x ->
// B re-read only 16x, A 8x... net -25%), BK=64, double-buffered (2 x 48 KB =
// 96 KB LDS), ONE barrier per K-iter. 1024-thread blocks, 16 waves =
// 4 row-groups (wr) x 2 col-halves (wc) x 2 K-halves (kh); each wave a 64x64
// tile over half of each BK=64 slab -> 16 waves/CU = 4/SIMD. Grid 256 =
// exactly 1 block/CU, no straggler tail. Per-CU-iter staged bytes drop
// 64->48 KB while the compute shadow stays ~16-wave sized -> less exposed
// delivery. K-half combine in 2 phases of 64 KB, lane-contiguous f32x4
// (R5-verified conflict-free). Swizzle (8 granules/row): (row,q) at q^(row&7);
// staging offset issue-invariant ((t&7)^((t>>3)&7)); frag reads 2 lanes/
// granule = free (R4/R6/R7-verified: 0 conflicts).
__global__ __launch_bounds__(1024, 4)
void gemm_gn_kernel(const unsigned short* __restrict__ A,  // [4096][2048] bf16
                    const unsigned short* __restrict__ W,  // [2048][2048] bf16
                    const float* __restrict__ bias,
                    const float* __restrict__ gnw,
                    const float* __restrict__ gnb,
                    float* __restrict__ out) {
    // buffer b at smem + b*24576: A tile (16384 shorts) then B tile (8192)
    __shared__ __align__(16) unsigned short smem[2 * 24576];  // 96 KB

    const int bc   = blockIdx.x;      // 0..15 col block (128 cols)
    const int br   = blockIdx.y;      // 0..15 row block (256 rows)
    const int t    = threadIdx.x;     // 0..1023
    const int lane = t & 63;
    const int wave = t >> 6;          // 0..15
    const int wr   = wave & 3;        // row group (64 rows each)
    const int wc   = (wave >> 2) & 1; // col half
    const int kh   = wave >> 3;       // K half (k offset kh*32 within BK=64)
    const int c16  = lane & 15;
    const int quad = lane >> 4;

    f32x4 acc[4][4];
#pragma unroll
    for (int i = 0; i < 4; i++)
#pragma unroll
        for (int j = 0; j < 4; j++) acc[i][j] = (f32x4){0.f, 0.f, 0.f, 0.f};

    // ---- staging addresses (1024 threads: 2 issues for A, 1 for B) ----
    // issue n (granule G = n*1024+t): row = n*128 + (t>>3), phys q' = t&7,
    // global q = (t&7)^(row&7) = (t&7)^((t>>3)&7)  (n*128 == 0 mod 8).
    const int r0 = t >> 3;                          // 0..127
    const int qo = ((t & 7) ^ (r0 & 7)) * 8;        // element offset in row
    const unsigned short* gA = A + (size_t)(br * 256 + r0) * C_IN + qo;
    const unsigned short* gB = W + (size_t)(bc * 128 + r0) * C_IN + qo;

#define STAGE(buf, k0)                                                                     \
    do {                                                                                   \
        unsigned short* sa = smem + (buf) * 24576;                                         \
        unsigned short* sb = sa + 16384;                                                   \
        _Pragma("unroll")                                                                  \
        for (int n = 0; n < 2; n++)                                                        \
            __builtin_amdgcn_global_load_lds(                                              \
                (const __attribute__((address_space(1))) void*)(gA + (size_t)(n * 128) * C_IN + (k0)), \
                (__attribute__((address_space(3))) void*)(sa + n * 8192 + t * 8), 16, 0, 0); \
        __builtin_amdgcn_global_load_lds(                                                  \
            (const __attribute__((address_space(1))) void*)(gB + (k0)),                    \
            (__attribute__((address_space(3))) void*)(sb + t * 8), 16, 0, 0);              \
    } while (0)

    // fragment read: logical granule q = kh*4+quad lives at phys q ^ (c16&7)
    const int qs = (((kh << 2) | quad) ^ (c16 & 7)) * 8;

    STAGE(0, 0);
    int cur = 0;
    for (int it = 0; it < 32; ++it) {
        __syncthreads();   // drains buf[cur] staging; all waves done with buf[cur^1]
        if (it < 31) STAGE(cur ^ 1, (it + 1) * 64);

        const unsigned short* sa = smem + cur * 24576;
        const unsigned short* sb = sa + 16384;
        bf16x8 a[4], b[4];
#pragma unroll
        for (int i = 0; i < 4; i++)
            a[i] = *(const bf16x8*)(sa + (wr * 64 + i * 16 + c16) * 64 + qs);
#pragma unroll
        for (int j = 0; j < 4; j++)
            b[j] = *(const bf16x8*)(sb + (wc * 64 + j * 16 + c16) * 64 + qs);
#pragma unroll
        for (int i = 0; i < 4; i++)
#pragma unroll
            for (int j = 0; j < 4; j++)
                acc[i][j] = __builtin_amdgcn_mfma_f32_16x16x32_bf16(a[i], b[j], acc[i][j], 0, 0, 0);
        cur ^= 1;
    }

    // ---- combine K-halves via LDS, 2 phases of 64 KB (96 KB smem) ----
    // Pair key (wr, wc); phase ph covers wr in {2ph, 2ph+1}. Region idx =
    // (wr&1)*2 + wc, 4 regions x 16 KB. Lane-contiguous: each (i,j) slab is
    // 64 lanes x 16 B = 1 KB contiguous -> 2 lanes/bank = free (R5-verified).
    __syncthreads();   // all MFMA reads of smem complete
    float* fbuf = (float*)smem;
    const int reg = ((wr & 1) * 2 + wc) * 4096;
#pragma unroll
    for (int ph = 0; ph < 2; ph++) {
        if (kh == 1 && (wr >> 1) == ph) {
#pragma unroll
            for (int i = 0; i < 4; i++)
#pragma unroll
                for (int j = 0; j < 4; j++)
                    *(f32x4*)(fbuf + reg + i * 1024 + j * 256 + lane * 4) = acc[i][j];
        }
        __syncthreads();
        if (kh == 0 && (wr >> 1) == ph) {
#pragma unroll
            for (int i = 0; i < 4; i++)
#pragma unroll
                for (int j = 0; j < 4; j++)
                    acc[i][j] += *(const f32x4*)(fbuf + reg + i * 1024 + j * 256 + lane * 4);
        }
        __syncthreads();
    }
    if (kh == 1) return;   // no further barriers below

    // ---- epilogue: bias + GroupNorm + hardtanh (kh==0 waves) ----
    // acc[i][j][r]: row = br*256 + wr*64 + i*16 + quad*4 + r,
    //               col = bc*128 + wc*64 + j*16 + c16. Wave's 64 cols = 1 group.
    const int colbase = bc * 128 + wc * 64;
    const int rowbase = br * 256 + wr * 64;
    float bv[4], gw[4], gb[4];
#pragma unroll
    for (int j = 0; j < 4; j++) {
        int col = colbase + j * 16 + c16;
        bv[j] = bias[col];
        gw[j] = gnw[col];
        gb[j] = gnb[col];
    }
#pragma unroll
    for (int i = 0; i < 4; i++) {
#pragma unroll
        for (int r = 0; r < 4; r++) {
            float s = 0.f, ss = 0.f;
#pragma unroll
            for (int j = 0; j < 4; j++) {
                float v = acc[i][j][r] + bv[j];
                acc[i][j][r] = v;
                s += v;
                ss += v * v;
            }
#pragma unroll
            for (int m = 1; m < 16; m <<= 1) {
                s  += __shfl_xor(s, m, 64);
                ss += __shfl_xor(ss, m, 64);
            }
            float mean = s * (1.f / 64.f);
            float var  = ss * (1.f / 64.f) - mean * mean;
            float rstd = rsqrtf(var + EPS);
            int row = rowbase + i * 16 + quad * 4 + r;
            float* orow = out + (size_t)row * C_OUT;
#pragma unroll
            for (int j = 0; j < 4; j++) {
                float v = (acc[i][j][r] - mean) * rstd * gw[j] + gb[j];
                v = fminf(1.f, fmaxf(-1.f, v));
                orow[colbase + j * 16 + c16] = v;
            }
        }
    }
}

extern "C" void kernel_launch(void* const* d_in, const int* in_sizes, int n_in,
                              void* d_out, int out_size, void* d_ws, size_t ws_size,
                              hipStream_t stream) {
    const float* x    = (const float*)d_in[0];   // [4096, 2048]
    const float* w    = (const float*)d_in[1];   // [2048, 2048]
    const float* bias = (const float*)d_in[2];   // [2048]
    const float* gnw  = (const float*)d_in[3];   // [2048]
    const float* gnb  = (const float*)d_in[4];   // [2048]
    float* out = (float*)d_out;

    unsigned short* xb = (unsigned short*)d_ws;                        // 16 MB
    unsigned short* wb = xb + (size_t)B_ROWS * C_IN;                   //  8 MB

    const int nx4 = B_ROWS * C_IN / 4;   // 2097152
    const int nw4 = C_OUT * C_IN / 4;    // 1048576
    cvt_f32_bf16_kernel<<<(nx4 + nw4 + 255) / 256, 256, 0, stream>>>(x, w, xb, wb, nx4, nw4);

    dim3 grid(C_OUT / 128, B_ROWS / 256);  // (16, 16) = 256 blocks = exactly 1/CU
    gemm_gn_kernel<<<grid, 1024, 0, stream>>>(xb, wb, bias, gnw, gnb, out);
}